// Round 1
// baseline (239.964 us; speedup 1.0000x reference)
//
#include <hip/hip_runtime.h>
#include <stdint.h>

// ---- problem constants (from reference) ----
#define NS 200000      // source nodes
#define NT 20000       // target nodes
#define SD 1024        // source dim (K)
#define ED 32          // embed dim (N of proj, D of agg)
#define TD 16          // target dim
#define NE 4000000     // edges

typedef __bf16 bf16x8 __attribute__((ext_vector_type(8)));
typedef float  f32x4  __attribute__((ext_vector_type(4)));
typedef int    i32x4  __attribute__((ext_vector_type(4)));
typedef unsigned int u32;
typedef unsigned short u16;

__device__ inline u16 f2bf_u(float f) {
    u32 u = __builtin_bit_cast(u32, f);
    u += 0x7fffu + ((u >> 16) & 1u);   // RNE (inputs are finite randoms; no NaN care needed)
    return (u16)(u >> 16);
}
__device__ inline __bf16 f2bf(float f) {
    u16 s = f2bf_u(f);
    return __builtin_bit_cast(__bf16, s);
}
__device__ inline float bf2f(u16 s) {
    u32 u = ((u32)s) << 16;
    return __builtin_bit_cast(float, u);
}

// ---------------------------------------------------------------------------
// Kernel 0: precompute B (embed) MFMA fragments in OUR k-bijection order.
// frag slot (kc, nt, lane l, elem j) holds embed[kc*32 + 8*(l>>4) + j][nt*16 + (l&15)]
// A-fragments use the identical bijection -> MFMA dot is exact regardless of
// the HW's internal k-order (slot-to-slot pairing cancels any permutation).
// ---------------------------------------------------------------------------
__global__ void bfrag_kernel(const float* __restrict__ embed,
                             u16* __restrict__ bfrag) {
    int tid = blockIdx.x * 64 + threadIdx.x;  // 4096 threads total
    int kc = tid >> 7;         // 0..31  K-chunk
    int nt = (tid >> 6) & 1;   // 0..1   N-tile
    int l  = tid & 63;         // lane slot
    int g = l >> 4, c = l & 15;
    int k0 = kc * 32 + g * 8;
    u16* dst = bfrag + ((size_t)(kc * 2 + nt) * 64 + l) * 8;
#pragma unroll
    for (int j = 0; j < 8; ++j) {
        dst[j] = f2bf_u(embed[(size_t)(k0 + j) * ED + nt * 16 + c]);
    }
}

// ---------------------------------------------------------------------------
// Kernel 1: x = bf16( (source_feat @ embed) / x_norm ), stored [NS][32] bf16.
// One wave per 16-row M-tile; 32 K-chunks of 32; 2 MFMA (n-tiles) per chunk.
// No LDS, no barriers: A fragments straight from global (fp32->bf16 in-flight),
// B fragments from the precomputed L2-resident buffer.
// ---------------------------------------------------------------------------
__global__ __launch_bounds__(256) void proj_kernel(
    const float* __restrict__ A, const float* __restrict__ xnorm,
    const u16* __restrict__ bfrag, u16* __restrict__ xout) {
    int w = threadIdx.x >> 6;          // wave 0..3
    int l = threadIdx.x & 63;
    int m = blockIdx.x * 4 + w;        // M-tile 0..12499 (200000/16)
    int g = l >> 4, c = l & 15;

    const float* arow = A + (size_t)(m * 16 + c) * SD + g * 8;
    const i32x4* bf = (const i32x4*)bfrag;

    f32x4 acc0 = {0.f, 0.f, 0.f, 0.f};
    f32x4 acc1 = {0.f, 0.f, 0.f, 0.f};

#pragma unroll 4
    for (int kc = 0; kc < 32; ++kc) {
        const float* ap = arow + kc * 32;
        f32x4 a0 = *(const f32x4*)(ap);
        f32x4 a1 = *(const f32x4*)(ap + 4);
        bf16x8 a;
        a[0] = f2bf(a0[0]); a[1] = f2bf(a0[1]); a[2] = f2bf(a0[2]); a[3] = f2bf(a0[3]);
        a[4] = f2bf(a1[0]); a[5] = f2bf(a1[1]); a[6] = f2bf(a1[2]); a[7] = f2bf(a1[3]);
        bf16x8 b0 = __builtin_bit_cast(bf16x8, bf[(kc * 2 + 0) * 64 + l]);
        bf16x8 b1 = __builtin_bit_cast(bf16x8, bf[(kc * 2 + 1) * 64 + l]);
        acc0 = __builtin_amdgcn_mfma_f32_16x16x32_bf16(a, b0, acc0, 0, 0, 0);
        acc1 = __builtin_amdgcn_mfma_f32_16x16x32_bf16(a, b1, acc1, 0, 0, 0);
    }

    // epilogue: C/D layout (HW-verified): col = lane&15, row = (lane>>4)*4 + reg
#pragma unroll
    for (int r = 0; r < 4; ++r) {
        int grow = m * 16 + g * 4 + r;
        float inv = 1.0f / xnorm[grow];
        xout[(size_t)grow * ED + c]      = f2bf_u(acc0[r] * inv);
        xout[(size_t)grow * ED + 16 + c] = f2bf_u(acc1[r] * inv);
    }
}

// ---------------------------------------------------------------------------
// Kernel 2: per-target mean over edge slice (edges target-sorted), fused with
// the [32]x[32x16] weight projection. One wave per target, 4 targets/block.
// Lane d = l&31 owns embed-dim d; halves (l>>5) process alternating edges.
// ---------------------------------------------------------------------------
__global__ __launch_bounds__(256) void agg_kernel(
    const u16* __restrict__ xbf, const int* __restrict__ edge_src,
    const int* __restrict__ range_list, const float* __restrict__ weight,
    float* __restrict__ out) {
    __shared__ float meanS[4][ED];
    __shared__ float Wl[ED * TD];

    int tid = threadIdx.x;
    // stage weight (512 floats, 256 threads x2)
    Wl[tid]       = weight[tid];
    Wl[tid + 256] = weight[tid + 256];

    int w = tid >> 6, l = tid & 63;
    int t = blockIdx.x * 4 + w;       // 5000 blocks * 4 = 20000 targets
    int start = range_list[2 * t];
    int end   = range_list[2 * t + 1];
    int d = l & 31, h = l >> 5;

    float acc = 0.f;
#pragma unroll 4
    for (int e = start + h; e < end; e += 2) {
        int sid = edge_src[e];                       // broadcast within half-wave
        acc += bf2f(xbf[(size_t)sid * ED + d]);      // 64B row per half-wave
    }
    acc += __shfl_xor(acc, 32);                       // merge the two halves

    int deg = end - start;
    float inv = 1.0f / (float)(deg > 0 ? deg : 1);
    if (l < 32) meanS[w][l] = acc * inv;
    __syncthreads();

    // projection: lanes 0..15 of each wave compute out[t][0..15]
    if (l < TD) {
        float o = 0.f;
#pragma unroll
        for (int dd = 0; dd < ED; ++dd) o += meanS[w][dd] * Wl[dd * TD + l];
        out[(size_t)t * TD + l] = o;
    }
}

// ---------------------------------------------------------------------------
extern "C" void kernel_launch(void* const* d_in, const int* in_sizes, int n_in,
                              void* d_out, int out_size, void* d_ws, size_t ws_size,
                              hipStream_t stream) {
    const float* source_feat = (const float*)d_in[0];
    const float* x_norm      = (const float*)d_in[1];
    const int*   edge_index  = (const int*)d_in[2];   // row 0 = src ids
    const int*   range_list  = (const int*)d_in[3];
    const float* embed       = (const float*)d_in[4];
    const float* weight      = (const float*)d_in[5];
    float* out = (float*)d_out;

    u16* bfrag = (u16*)d_ws;                               // 64 KB
    u16* xbf   = (u16*)((char*)d_ws + 65536);              // 12.8 MB (NS*32*2)

    hipLaunchKernelGGL(bfrag_kernel, dim3(64),   dim3(64),  0, stream, embed, bfrag);
    hipLaunchKernelGGL(proj_kernel,  dim3(3125), dim3(256), 0, stream,
                       source_feat, x_norm, bfrag, xbf);
    hipLaunchKernelGGL(agg_kernel,   dim3(5000), dim3(256), 0, stream,
                       xbf, edge_index, range_list, weight, out);
}

// Round 2
// 238.058 us; speedup vs baseline: 1.0080x; 1.0080x over previous
//
#include <hip/hip_runtime.h>
#include <stdint.h>

// ---- problem constants (from reference) ----
#define NS 200000      // source nodes
#define NT 20000       // target nodes
#define SD 1024        // source dim (K)
#define ED 32          // embed dim (N of proj, D of agg)
#define TD 16          // target dim
#define NE 4000000     // edges

typedef __bf16 bf16x8 __attribute__((ext_vector_type(8)));
typedef float  f32x4  __attribute__((ext_vector_type(4)));
typedef int    i32x4  __attribute__((ext_vector_type(4)));
typedef unsigned int u32;
typedef unsigned short u16;

__device__ inline u16 f2bf_u(float f) {
    u32 u = __builtin_bit_cast(u32, f);
    u += 0x7fffu + ((u >> 16) & 1u);   // RNE
    return (u16)(u >> 16);
}

// ---------------------------------------------------------------------------
// Kernel 0: precompute B (embed) MFMA fragments in OUR k-bijection order.
// frag slot (kc, nt, lane l, elem j) holds embed[kc*32 + 8*(l>>4) + j][nt*16 + (l&15)]
// A-fragments use the identical bijection -> MFMA dot is exact regardless of
// the HW's internal k-order (slot-to-slot pairing cancels any permutation).
// ---------------------------------------------------------------------------
__global__ void bfrag_kernel(const float* __restrict__ embed,
                             u16* __restrict__ bfrag) {
    int tid = blockIdx.x * 64 + threadIdx.x;  // 4096 threads total
    int kc = tid >> 7;         // 0..31  K-chunk
    int nt = (tid >> 6) & 1;   // 0..1   N-tile
    int l  = tid & 63;         // lane slot
    int g = l >> 4, c = l & 15;
    int k0 = kc * 32 + g * 8;
    u16* dst = bfrag + ((size_t)(kc * 2 + nt) * 64 + l) * 8;
#pragma unroll
    for (int j = 0; j < 8; ++j) {
        dst[j] = f2bf_u(embed[(size_t)(k0 + j) * ED + nt * 16 + c]);
    }
}

// ---------------------------------------------------------------------------
// Kernel 1: x = bf16( (source_feat @ embed) / x_norm ), stored [NS][32] bf16.
// One wave per 16-row M-tile; 32 K-chunks of 32; 2 MFMA (n-tiles) per chunk.
// No LDS, no barriers. fp32->bf16 via compiler casts (v_cvt_pk_bf16_f32).
// ---------------------------------------------------------------------------
__global__ __launch_bounds__(256) void proj_kernel(
    const float* __restrict__ A, const float* __restrict__ xnorm,
    const u16* __restrict__ bfrag, u16* __restrict__ xout) {
    int w = threadIdx.x >> 6;          // wave 0..3
    int l = threadIdx.x & 63;
    int m = blockIdx.x * 4 + w;        // M-tile 0..12499 (200000/16)
    int g = l >> 4, c = l & 15;

    const float* arow = A + (size_t)(m * 16 + c) * SD + g * 8;
    const i32x4* bf = (const i32x4*)bfrag;

    f32x4 acc0 = {0.f, 0.f, 0.f, 0.f};
    f32x4 acc1 = {0.f, 0.f, 0.f, 0.f};

#pragma unroll 4
    for (int kc = 0; kc < 32; ++kc) {
        const float* ap = arow + kc * 32;
        f32x4 a0 = *(const f32x4*)(ap);
        f32x4 a1 = *(const f32x4*)(ap + 4);
        bf16x8 a;
        a[0] = (__bf16)a0[0]; a[1] = (__bf16)a0[1];
        a[2] = (__bf16)a0[2]; a[3] = (__bf16)a0[3];
        a[4] = (__bf16)a1[0]; a[5] = (__bf16)a1[1];
        a[6] = (__bf16)a1[2]; a[7] = (__bf16)a1[3];
        bf16x8 b0 = __builtin_bit_cast(bf16x8, bf[(kc * 2 + 0) * 64 + l]);
        bf16x8 b1 = __builtin_bit_cast(bf16x8, bf[(kc * 2 + 1) * 64 + l]);
        acc0 = __builtin_amdgcn_mfma_f32_16x16x32_bf16(a, b0, acc0, 0, 0, 0);
        acc1 = __builtin_amdgcn_mfma_f32_16x16x32_bf16(a, b1, acc1, 0, 0, 0);
    }

    // epilogue: C/D layout (HW-verified): col = lane&15, row = (lane>>4)*4 + reg
#pragma unroll
    for (int r = 0; r < 4; ++r) {
        int grow = m * 16 + g * 4 + r;
        float inv = 1.0f / xnorm[grow];
        __bf16 v0 = (__bf16)(acc0[r] * inv);
        __bf16 v1 = (__bf16)(acc1[r] * inv);
        xout[(size_t)grow * ED + c]      = __builtin_bit_cast(u16, v0);
        xout[(size_t)grow * ED + 16 + c] = __builtin_bit_cast(u16, v1);
    }
}

// ---------------------------------------------------------------------------
// Kernel 2: per-target mean over edge slice (edges target-sorted), fused with
// the [32]x[32x16] weight projection. One wave per target, 4 targets/block.
// 16 edges per wave-iteration: 4 lanes/edge, each lane dwordx4 (8 bf16 dims).
// ---------------------------------------------------------------------------
__global__ __launch_bounds__(256) void agg_kernel(
    const u16* __restrict__ xbf, const int* __restrict__ edge_src,
    const int* __restrict__ range_list, const float* __restrict__ weight,
    float* __restrict__ out) {
    __shared__ float meanS[4][ED];
    __shared__ float Wl[ED * TD];

    int tid = threadIdx.x;
    // stage weight (512 floats, 256 threads x2)
    Wl[tid]       = weight[tid];
    Wl[tid + 256] = weight[tid + 256];

    int w = tid >> 6, l = tid & 63;
    int t = blockIdx.x * 4 + w;       // 5000 blocks * 4 = 20000 targets
    int start = range_list[2 * t];
    int end   = range_list[2 * t + 1];
    int grp = l >> 2;                 // 0..15: edge slot within iteration
    int qd  = l & 3;                  // quarter-row: dims qd*8 .. qd*8+7

    float acc[8];
#pragma unroll
    for (int j = 0; j < 8; ++j) acc[j] = 0.f;

    for (int e0 = start; e0 < end; e0 += 16) {
        int e = e0 + grp;
        if (e < end) {
            int sid = edge_src[e];    // 16 distinct ids, 4 lanes each
            i32x4 v = *(const i32x4*)(xbf + (size_t)sid * ED + qd * 8);
#pragma unroll
            for (int j = 0; j < 4; ++j) {
                u32 u = (u32)v[j];
                acc[2 * j]     += __builtin_bit_cast(float, u << 16);
                acc[2 * j + 1] += __builtin_bit_cast(float, u & 0xffff0000u);
            }
        }
    }

    // reduce over the 16 edge-groups (xor 4,8,16,32)
#pragma unroll
    for (int m = 4; m <= 32; m <<= 1) {
#pragma unroll
        for (int j = 0; j < 8; ++j) acc[j] += __shfl_xor(acc[j], m);
    }

    int deg = end - start;
    float inv = 1.0f / (float)(deg > 0 ? deg : 1);
    if (l < 4) {                       // lanes 0..3 hold qd=0..3, grp=0
#pragma unroll
        for (int j = 0; j < 8; ++j) meanS[w][qd * 8 + j] = acc[j] * inv;
    }
    __syncthreads();

    // projection: lanes 0..15 of each wave compute out[t][0..15]
    if (l < TD) {
        float o = 0.f;
#pragma unroll
        for (int dd = 0; dd < ED; ++dd) o += meanS[w][dd] * Wl[dd * TD + l];
        out[(size_t)t * TD + l] = o;
    }
}

// ---------------------------------------------------------------------------
extern "C" void kernel_launch(void* const* d_in, const int* in_sizes, int n_in,
                              void* d_out, int out_size, void* d_ws, size_t ws_size,
                              hipStream_t stream) {
    const float* source_feat = (const float*)d_in[0];
    const float* x_norm      = (const float*)d_in[1];
    const int*   edge_index  = (const int*)d_in[2];   // row 0 = src ids
    const int*   range_list  = (const int*)d_in[3];
    const float* embed       = (const float*)d_in[4];
    const float* weight      = (const float*)d_in[5];
    float* out = (float*)d_out;

    u16* bfrag = (u16*)d_ws;                               // 64 KB
    u16* xbf   = (u16*)((char*)d_ws + 65536);              // 12.8 MB (NS*32*2)

    hipLaunchKernelGGL(bfrag_kernel, dim3(64),   dim3(64),  0, stream, embed, bfrag);
    hipLaunchKernelGGL(proj_kernel,  dim3(3125), dim3(256), 0, stream,
                       source_feat, x_norm, bfrag, xbf);
    hipLaunchKernelGGL(agg_kernel,   dim3(5000), dim3(256), 0, stream,
                       xbf, edge_index, range_list, weight, out);
}